// Round 4
// baseline (340.590 us; speedup 1.0000x reference)
//
#include <hip/hip_runtime.h>
#include <math.h>

// ClassicMHSA via split-bf16 MFMA, LDS-free flash attention (swapped QK^T),
// round 4: in-block split-K (8 waves: 2 key-halves x 4 query-strips) for 2x
// occupancy (grid was the limiter: 1024 blocks x 4 waves = 16 waves/CU).
// Partials merged exactly in LDS (flash combine), so accuracy is unchanged.
//
//  1) xt_split : X[b][c][n] f32 -> Xthi/Xtlo [b][n][c] bf16
//  2) qkv_proj : MFMA GEMM -> Qhi/Qlo, Khi/Klo [bh][n][32], Vthi [bh][32][n]
//  3) attn_mfma: flash attention. QK^T 3-pass split-bf16, PV 1-pass bf16,
//     softmax in-register (swapped-QK^T makes each lane own one query).

#define B_   2
#define CIN  256
#define COUT 768
#define NH   8
#define HD   32
#define NTOK 4096
#define BH   (B_*NH)

typedef __attribute__((ext_vector_type(8))) short bf16x8;
typedef __attribute__((ext_vector_type(4))) float f32x4;

static __device__ __forceinline__ unsigned short f2bf(float f) {  // RNE
  unsigned u = __float_as_uint(f);
  unsigned r = ((u >> 16) & 1u) + 0x7fffu;
  return (unsigned short)((u + r) >> 16);
}
static __device__ __forceinline__ float bf2f(unsigned short h) {
  return __uint_as_float(((unsigned)h) << 16);
}
// pack two POSITIVE floats to bf16 pair (round-half-up; p in (0,1])
static __device__ __forceinline__ unsigned packbf(float lo, float hi) {
  unsigned a = (__float_as_uint(lo) + 0x8000u) >> 16;
  unsigned b = (__float_as_uint(hi) + 0x8000u) & 0xffff0000u;
  return a | b;
}

// ---------------- 1) X transpose + split (coalesced, LDS transpose) --------
__global__ __launch_bounds__(256) void xt_split(
    const float* __restrict__ X,
    unsigned short* __restrict__ Xthi, unsigned short* __restrict__ Xtlo) {
  __shared__ unsigned tile[64][72];  // hi | lo<<16
  const int t = threadIdx.x;
  const int n0 = blockIdx.x * 64, c0 = blockIdx.y * 64, b = blockIdx.z;
  {
    const int cl = t >> 2, nb = (t & 3) * 16;
    const float* src = &X[((size_t)(b * CIN + c0 + cl)) * NTOK + n0 + nb];
#pragma unroll
    for (int q = 0; q < 4; ++q) {
      float4 v = *(const float4*)&src[4 * q];
      float vv[4] = {v.x, v.y, v.z, v.w};
#pragma unroll
      for (int e = 0; e < 4; ++e) {
        unsigned short h = f2bf(vv[e]);
        unsigned short l = f2bf(vv[e] - bf2f(h));
        tile[cl][nb + 4 * q + e] = (unsigned)h | ((unsigned)l << 16);
      }
    }
  }
  __syncthreads();
  {
    const int nl = t >> 2, cb = (t & 3) * 16;
    unsigned wh[8], wl[8];
#pragma unroll
    for (int j = 0; j < 8; ++j) {
      unsigned a = tile[cb + 2 * j][nl];
      unsigned bb = tile[cb + 2 * j + 1][nl];
      wh[j] = (a & 0xffffu) | (bb << 16);
      wl[j] = (a >> 16) | (bb & 0xffff0000u);
    }
    size_t base = ((size_t)b * NTOK + n0 + nl) * CIN + c0 + cb;
    uint4 u0, u1;
    u0.x = wh[0]; u0.y = wh[1]; u0.z = wh[2]; u0.w = wh[3];
    u1.x = wh[4]; u1.y = wh[5]; u1.z = wh[6]; u1.w = wh[7];
    *(uint4*)&Xthi[base] = u0;
    *(uint4*)&Xthi[base + 8] = u1;
    u0.x = wl[0]; u0.y = wl[1]; u0.z = wl[2]; u0.w = wl[3];
    u1.x = wl[4]; u1.y = wl[5]; u1.z = wl[6]; u1.w = wl[7];
    *(uint4*)&Xtlo[base] = u0;
    *(uint4*)&Xtlo[base + 8] = u1;
  }
}

// ---------------- 2) QKV projection (MFMA, no LDS) ----------------
__global__ __launch_bounds__(256) void qkv_proj(
    const float* __restrict__ W, const float* __restrict__ bias,
    const unsigned short* __restrict__ Xthi, const unsigned short* __restrict__ Xtlo,
    unsigned short* __restrict__ Qhi, unsigned short* __restrict__ Qlo,
    unsigned short* __restrict__ Khi, unsigned short* __restrict__ Klo,
    unsigned short* __restrict__ Vthi) {
  const int t = threadIdx.x;
  const int w = t >> 6, lane = t & 63, m = lane & 15, hi4 = lane >> 4;
  const int o0 = blockIdx.x * 64, n0 = blockIdx.y * 64, b = blockIdx.z;

  const int orow = o0 + 16 * w + m;
  f32x4 zero = {0.f, 0.f, 0.f, 0.f};
  f32x4 acc[4] = {zero, zero, zero, zero};

  for (int cs = 0; cs < CIN; cs += 32) {
    const float* wp = &W[(size_t)orow * CIN + cs + 8 * hi4];
    float4 wa = *(const float4*)wp;
    float4 wb = *(const float4*)(wp + 4);
    float wf[8] = {wa.x, wa.y, wa.z, wa.w, wb.x, wb.y, wb.z, wb.w};
    bf16x8 awh, awl;
#pragma unroll
    for (int k = 0; k < 8; ++k) {
      unsigned short h = f2bf(wf[k]);
      awh[k] = (short)h;
      awl[k] = (short)f2bf(wf[k] - bf2f(h));
    }
#pragma unroll
    for (int jt = 0; jt < 4; ++jt) {
      size_t xi = ((size_t)b * NTOK + n0 + 16 * jt + m) * CIN + cs + 8 * hi4;
      bf16x8 bxh = *(const bf16x8*)&Xthi[xi];
      bf16x8 bxl = *(const bf16x8*)&Xtlo[xi];
      acc[jt] = __builtin_amdgcn_mfma_f32_16x16x32_bf16(awl, bxh, acc[jt], 0, 0, 0);
      acc[jt] = __builtin_amdgcn_mfma_f32_16x16x32_bf16(awh, bxl, acc[jt], 0, 0, 0);
      acc[jt] = __builtin_amdgcn_mfma_f32_16x16x32_bf16(awh, bxh, acc[jt], 0, 0, 0);
    }
  }

  const int qkv = o0 >> 8;
  const int ohd = (o0 & 255) + 16 * w;
  const int h = ohd >> 5;
  const int cb = (ohd & 31) + 4 * hi4;
  const int bh = b * NH + h;
  float bs[4];
#pragma unroll
  for (int r = 0; r < 4; ++r) bs[r] = bias[o0 + 16 * w + 4 * hi4 + r];

#pragma unroll
  for (int jt = 0; jt < 4; ++jt) {
    const int n = n0 + 16 * jt + m;
    unsigned short ph[4], pl[4];
#pragma unroll
    for (int r = 0; r < 4; ++r) {
      float y = acc[jt][r] + bs[r];
      ph[r] = f2bf(y);
      pl[r] = f2bf(y - bf2f(ph[r]));
    }
    if (qkv < 2) {  // Q/K: [bh][n][32] hi+lo
      unsigned short* dh = (qkv == 0 ? Qhi : Khi);
      unsigned short* dl = (qkv == 0 ? Qlo : Klo);
      size_t idx = ((size_t)bh * NTOK + n) * HD + cb;
      *(ushort4*)&dh[idx] = make_ushort4(ph[0], ph[1], ph[2], ph[3]);
      *(ushort4*)&dl[idx] = make_ushort4(pl[0], pl[1], pl[2], pl[3]);
    } else {  // V: [bh][32][n] hi only
#pragma unroll
      for (int r = 0; r < 4; ++r)
        Vthi[((size_t)bh * HD + cb + r) * NTOK + n] = ph[r];
    }
  }
}

// ---------------- 3) Flash attention (in-block split-K, 8 waves) ----------
// grid (NTOK/64, BH), block 512. Wave w: half=w>>2 (keys half*2048..+2048),
// wsub=w&3 (queries i0+16*wsub..+15). lane 16g+m owns query i=16*wsub+m.
// Ends with exact flash combine of the two halves through LDS.
__global__ __launch_bounds__(512, 8) void attn_mfma(
    const unsigned short* __restrict__ Qhi, const unsigned short* __restrict__ Qlo,
    const unsigned short* __restrict__ Khi, const unsigned short* __restrict__ Klo,
    const unsigned short* __restrict__ Vthi, float* __restrict__ out) {
  __shared__ float Opart[2][64][33];  // pad 33: partial-write banks (33m+c)%32 distinct
  __shared__ float Mpart[2][64], Lpart[2][64];

  const int t = threadIdx.x;
  const int w = t >> 6, lane = t & 63, m = lane & 15, g = lane >> 4;
  const int half = w >> 2, wsub = w & 3;
  const int i0 = blockIdx.x * 64;
  const int bh = blockIdx.y;

  size_t qi = ((size_t)bh * NTOK + i0 + 16 * wsub + m) * HD + 8 * g;
  const bf16x8 qh = *(const bf16x8*)&Qhi[qi];
  const bf16x8 ql = *(const bf16x8*)&Qlo[qi];

  const unsigned short* Kb_h = Khi + (size_t)bh * NTOK * HD;
  const unsigned short* Kb_l = Klo + (size_t)bh * NTOK * HD;
  const unsigned short* Vb   = Vthi + (size_t)bh * HD * NTOK;

  f32x4 zero = {0.f, 0.f, 0.f, 0.f};
  f32x4 oacc[2] = {zero, zero};  // D[c=16ct+4g+r][i=m]
  float mrun = -1e30f, lrun = 0.f;
  const float scale = 0.17677669529663688f;  // 1/sqrt(32)

  const int srcA = (g & 1) * 32 + m;  // P B-frag gather base lane
  const bool ghi = (g >= 2);

  const int jbeg = half * (NTOK / 2), jend = jbeg + NTOK / 2;
  for (int j0 = jbeg; j0 < jend; j0 += 64) {
    bf16x8 kf_h[4], kf_l[4], vf[2][2];
#pragma unroll
    for (int jt = 0; jt < 4; ++jt) {
      size_t ki = (size_t)(j0 + 16 * jt + m) * HD + 8 * g;
      kf_h[jt] = *(const bf16x8*)&Kb_h[ki];
      kf_l[jt] = *(const bf16x8*)&Kb_l[ki];
    }
#pragma unroll
    for (int k2 = 0; k2 < 2; ++k2)
#pragma unroll
      for (int ct = 0; ct < 2; ++ct)
        vf[k2][ct] = *(const bf16x8*)&Vb[(size_t)(16 * ct + m) * NTOK + j0 + 32 * k2 + 8 * g];

    // ---- S^T tiles: rows j=4g+r, col i=m (3-pass split-bf16) ----
    f32x4 s[4];
#pragma unroll
    for (int jt = 0; jt < 4; ++jt) {
      f32x4 a = zero;
      a = __builtin_amdgcn_mfma_f32_16x16x32_bf16(kf_l[jt], qh, a, 0, 0, 0);
      a = __builtin_amdgcn_mfma_f32_16x16x32_bf16(kf_h[jt], ql, a, 0, 0, 0);
      a = __builtin_amdgcn_mfma_f32_16x16x32_bf16(kf_h[jt], qh, a, 0, 0, 0);
#pragma unroll
      for (int r = 0; r < 4; ++r) s[jt][r] = a[r] * scale;
    }

    // ---- online softmax for query i=m ----
    float mx = s[0][0];
#pragma unroll
    for (int jt = 0; jt < 4; ++jt)
#pragma unroll
      for (int r = 0; r < 4; ++r) mx = fmaxf(mx, s[jt][r]);
    mx = fmaxf(mx, __shfl_xor(mx, 16, 64));
    mx = fmaxf(mx, __shfl_xor(mx, 32, 64));
    const float mnew = fmaxf(mrun, mx);
    const float sf = __expf(mrun - mnew);
    mrun = mnew;

    float rsum = 0.f;
    unsigned pw[4][2];
#pragma unroll
    for (int jt = 0; jt < 4; ++jt) {
      float p0 = __expf(s[jt][0] - mnew);
      float p1 = __expf(s[jt][1] - mnew);
      float p2 = __expf(s[jt][2] - mnew);
      float p3 = __expf(s[jt][3] - mnew);
      rsum += (p0 + p1) + (p2 + p3);
      pw[jt][0] = packbf(p0, p1);
      pw[jt][1] = packbf(p2, p3);
    }
    rsum += __shfl_xor(rsum, 16, 64);
    rsum += __shfl_xor(rsum, 32, 64);
    lrun = lrun * sf + rsum;
#pragma unroll
    for (int ct = 0; ct < 2; ++ct)
#pragma unroll
      for (int r = 0; r < 4; ++r) oacc[ct][r] *= sf;

    // ---- PV: A=V(rows c), B=P (assembled in-register) ----
#pragma unroll
    for (int k2 = 0; k2 < 2; ++k2) {
      const int tA = 2 * k2, tB = 2 * k2 + 1;
      unsigned w0a = __shfl((int)pw[tA][0], srcA, 64);
      unsigned w1a = __shfl((int)pw[tA][1], srcA, 64);
      unsigned w2a = __shfl((int)pw[tA][0], srcA + 16, 64);
      unsigned w3a = __shfl((int)pw[tA][1], srcA + 16, 64);
      unsigned w0b = __shfl((int)pw[tB][0], srcA, 64);
      unsigned w1b = __shfl((int)pw[tB][1], srcA, 64);
      unsigned w2b = __shfl((int)pw[tB][0], srcA + 16, 64);
      unsigned w3b = __shfl((int)pw[tB][1], srcA + 16, 64);
      union { unsigned u[4]; bf16x8 v; } pf;
      pf.u[0] = ghi ? w0b : w0a;
      pf.u[1] = ghi ? w1b : w1a;
      pf.u[2] = ghi ? w2b : w2a;
      pf.u[3] = ghi ? w3b : w3a;
      oacc[0] = __builtin_amdgcn_mfma_f32_16x16x32_bf16(vf[k2][0], pf.v, oacc[0], 0, 0, 0);
      oacc[1] = __builtin_amdgcn_mfma_f32_16x16x32_bf16(vf[k2][1], pf.v, oacc[1], 0, 0, 0);
    }
  }

  // ---- stash partials (pre-division numerators + m,l) ----
#pragma unroll
  for (int ct = 0; ct < 2; ++ct)
#pragma unroll
    for (int r = 0; r < 4; ++r)
      Opart[half][16 * wsub + m][16 * ct + 4 * g + r] = oacc[ct][r];
  if (lane < 16) {  // g==0, m==lane: all lanes hold the reduced m,l
    Mpart[half][16 * wsub + lane] = mrun;
    Lpart[half][16 * wsub + lane] = lrun;
  }
  __syncthreads();

  // ---- exact flash combine + store: thread t -> query q=t>>3, c=(t&7)*4.. ----
  {
    const int q = t >> 3, cb = (t & 7) * 4;
    const float m0 = Mpart[0][q], m1 = Mpart[1][q];
    const float M = fmaxf(m0, m1);
    const float e0 = __expf(m0 - M), e1 = __expf(m1 - M);
    const float inv = 1.0f / (Lpart[0][q] * e0 + Lpart[1][q] * e1);
    const int b = bh >> 3, h = bh & 7;
    float* og = out + ((size_t)b * CIN + h * HD) * NTOK + i0 + q;
#pragma unroll
    for (int u = 0; u < 4; ++u) {
      const int c = cb + u;
      og[(size_t)c * NTOK] =
          (Opart[0][q][c] * e0 + Opart[1][q][c] * e1) * inv;
    }
  }
}

extern "C" void kernel_launch(void* const* d_in, const int* in_sizes, int n_in,
                              void* d_out, int out_size, void* d_ws, size_t ws_size,
                              hipStream_t stream) {
  const float* x    = (const float*)d_in[0];
  const float* w    = (const float*)d_in[1];
  const float* bias = (const float*)d_in[2];
  float* outp = (float*)d_out;

  // Xt (split bf16) in d_out scratch: 8,388,608 B = out bytes.
  unsigned short* Xthi = (unsigned short*)d_out;
  unsigned short* Xtlo = Xthi + (size_t)B_ * NTOK * CIN;

  // ws: 5 arrays x 4 MB = 20 MB (<= 25.17 MB proven in rounds 1-2)
  unsigned short* ws = (unsigned short*)d_ws;
  const size_t SZ = (size_t)BH * NTOK * HD;
  unsigned short* Qhi_ = ws + 0 * SZ;
  unsigned short* Qlo_ = ws + 1 * SZ;
  unsigned short* Khi_ = ws + 2 * SZ;
  unsigned short* Klo_ = ws + 3 * SZ;
  unsigned short* Vthi_ = ws + 4 * SZ;

  xt_split<<<dim3(NTOK / 64, CIN / 64, B_), 256, 0, stream>>>(x, Xthi, Xtlo);
  qkv_proj<<<dim3(COUT / 64, NTOK / 64, B_), 256, 0, stream>>>(
      w, bias, Xthi, Xtlo, Qhi_, Qlo_, Khi_, Klo_, Vthi_);
  attn_mfma<<<dim3(NTOK / 64, BH), 512, 0, stream>>>(
      Qhi_, Qlo_, Khi_, Klo_, Vthi_, outp);
}

// Round 5
// 296.573 us; speedup vs baseline: 1.1484x; 1.1484x over previous
//
#include <hip/hip_runtime.h>
#include <math.h>

// ClassicMHSA via split-bf16 MFMA, LDS-free flash attention (swapped QK^T).
// Round 5: revert split-K (r4 regression: occupancy was not binding; scattered
// combine-store cost 80MB writes). Add (1) XCD-locality swizzle so each XCD's
// L2 serves only 2 bh's K/V (1.5MB, L2-resident), (2) register double-buffer
// K-prefetch so the softmax/PV chain hides next-tile K latency.
//
//  1) xt_split : X[b][c][n] f32 -> Xthi/Xtlo [b][n][c] bf16
//  2) qkv_proj : MFMA GEMM -> Qhi/Qlo, Khi/Klo [bh][n][32], Vthi [bh][32][n]
//  3) attn_mfma: flash attention. QK^T 3-pass split-bf16, PV 1-pass bf16,
//     softmax in-register (swapped QK^T: each lane owns one query).

#define B_   2
#define CIN  256
#define COUT 768
#define NH   8
#define HD   32
#define NTOK 4096
#define BH   (B_*NH)

typedef __attribute__((ext_vector_type(8))) short bf16x8;
typedef __attribute__((ext_vector_type(4))) float f32x4;

static __device__ __forceinline__ unsigned short f2bf(float f) {  // RNE
  unsigned u = __float_as_uint(f);
  unsigned r = ((u >> 16) & 1u) + 0x7fffu;
  return (unsigned short)((u + r) >> 16);
}
static __device__ __forceinline__ float bf2f(unsigned short h) {
  return __uint_as_float(((unsigned)h) << 16);
}
// pack two POSITIVE floats to bf16 pair (round-half-up; p in (0,1])
static __device__ __forceinline__ unsigned packbf(float lo, float hi) {
  unsigned a = (__float_as_uint(lo) + 0x8000u) >> 16;
  unsigned b = (__float_as_uint(hi) + 0x8000u) & 0xffff0000u;
  return a | b;
}

// ---------------- 1) X transpose + split (coalesced, LDS transpose) --------
__global__ __launch_bounds__(256) void xt_split(
    const float* __restrict__ X,
    unsigned short* __restrict__ Xthi, unsigned short* __restrict__ Xtlo) {
  __shared__ unsigned tile[64][72];  // hi | lo<<16
  const int t = threadIdx.x;
  const int n0 = blockIdx.x * 64, c0 = blockIdx.y * 64, b = blockIdx.z;
  {
    const int cl = t >> 2, nb = (t & 3) * 16;
    const float* src = &X[((size_t)(b * CIN + c0 + cl)) * NTOK + n0 + nb];
#pragma unroll
    for (int q = 0; q < 4; ++q) {
      float4 v = *(const float4*)&src[4 * q];
      float vv[4] = {v.x, v.y, v.z, v.w};
#pragma unroll
      for (int e = 0; e < 4; ++e) {
        unsigned short h = f2bf(vv[e]);
        unsigned short l = f2bf(vv[e] - bf2f(h));
        tile[cl][nb + 4 * q + e] = (unsigned)h | ((unsigned)l << 16);
      }
    }
  }
  __syncthreads();
  {
    const int nl = t >> 2, cb = (t & 3) * 16;
    unsigned wh[8], wl[8];
#pragma unroll
    for (int j = 0; j < 8; ++j) {
      unsigned a = tile[cb + 2 * j][nl];
      unsigned bb = tile[cb + 2 * j + 1][nl];
      wh[j] = (a & 0xffffu) | (bb << 16);
      wl[j] = (a >> 16) | (bb & 0xffff0000u);
    }
    size_t base = ((size_t)b * NTOK + n0 + nl) * CIN + c0 + cb;
    uint4 u0, u1;
    u0.x = wh[0]; u0.y = wh[1]; u0.z = wh[2]; u0.w = wh[3];
    u1.x = wh[4]; u1.y = wh[5]; u1.z = wh[6]; u1.w = wh[7];
    *(uint4*)&Xthi[base] = u0;
    *(uint4*)&Xthi[base + 8] = u1;
    u0.x = wl[0]; u0.y = wl[1]; u0.z = wl[2]; u0.w = wl[3];
    u1.x = wl[4]; u1.y = wl[5]; u1.z = wl[6]; u1.w = wl[7];
    *(uint4*)&Xtlo[base] = u0;
    *(uint4*)&Xtlo[base + 8] = u1;
  }
}

// ---------------- 2) QKV projection (MFMA, no LDS) ----------------
__global__ __launch_bounds__(256) void qkv_proj(
    const float* __restrict__ W, const float* __restrict__ bias,
    const unsigned short* __restrict__ Xthi, const unsigned short* __restrict__ Xtlo,
    unsigned short* __restrict__ Qhi, unsigned short* __restrict__ Qlo,
    unsigned short* __restrict__ Khi, unsigned short* __restrict__ Klo,
    unsigned short* __restrict__ Vthi) {
  const int t = threadIdx.x;
  const int w = t >> 6, lane = t & 63, m = lane & 15, hi4 = lane >> 4;
  const int o0 = blockIdx.x * 64, n0 = blockIdx.y * 64, b = blockIdx.z;

  const int orow = o0 + 16 * w + m;
  f32x4 zero = {0.f, 0.f, 0.f, 0.f};
  f32x4 acc[4] = {zero, zero, zero, zero};

  for (int cs = 0; cs < CIN; cs += 32) {
    const float* wp = &W[(size_t)orow * CIN + cs + 8 * hi4];
    float4 wa = *(const float4*)wp;
    float4 wb = *(const float4*)(wp + 4);
    float wf[8] = {wa.x, wa.y, wa.z, wa.w, wb.x, wb.y, wb.z, wb.w};
    bf16x8 awh, awl;
#pragma unroll
    for (int k = 0; k < 8; ++k) {
      unsigned short h = f2bf(wf[k]);
      awh[k] = (short)h;
      awl[k] = (short)f2bf(wf[k] - bf2f(h));
    }
#pragma unroll
    for (int jt = 0; jt < 4; ++jt) {
      size_t xi = ((size_t)b * NTOK + n0 + 16 * jt + m) * CIN + cs + 8 * hi4;
      bf16x8 bxh = *(const bf16x8*)&Xthi[xi];
      bf16x8 bxl = *(const bf16x8*)&Xtlo[xi];
      acc[jt] = __builtin_amdgcn_mfma_f32_16x16x32_bf16(awl, bxh, acc[jt], 0, 0, 0);
      acc[jt] = __builtin_amdgcn_mfma_f32_16x16x32_bf16(awh, bxl, acc[jt], 0, 0, 0);
      acc[jt] = __builtin_amdgcn_mfma_f32_16x16x32_bf16(awh, bxh, acc[jt], 0, 0, 0);
    }
  }

  const int qkv = o0 >> 8;
  const int ohd = (o0 & 255) + 16 * w;
  const int h = ohd >> 5;
  const int cb = (ohd & 31) + 4 * hi4;
  const int bh = b * NH + h;
  float bs[4];
#pragma unroll
  for (int r = 0; r < 4; ++r) bs[r] = bias[o0 + 16 * w + 4 * hi4 + r];

#pragma unroll
  for (int jt = 0; jt < 4; ++jt) {
    const int n = n0 + 16 * jt + m;
    unsigned short ph[4], pl[4];
#pragma unroll
    for (int r = 0; r < 4; ++r) {
      float y = acc[jt][r] + bs[r];
      ph[r] = f2bf(y);
      pl[r] = f2bf(y - bf2f(ph[r]));
    }
    if (qkv < 2) {  // Q/K: [bh][n][32] hi+lo
      unsigned short* dh = (qkv == 0 ? Qhi : Khi);
      unsigned short* dl = (qkv == 0 ? Qlo : Klo);
      size_t idx = ((size_t)bh * NTOK + n) * HD + cb;
      *(ushort4*)&dh[idx] = make_ushort4(ph[0], ph[1], ph[2], ph[3]);
      *(ushort4*)&dl[idx] = make_ushort4(pl[0], pl[1], pl[2], pl[3]);
    } else {  // V: [bh][32][n] hi only
#pragma unroll
      for (int r = 0; r < 4; ++r)
        Vthi[((size_t)bh * HD + cb + r) * NTOK + n] = ph[r];
    }
  }
}

// ---------------- 3) Flash attention (LDS-free, K-prefetch, XCD swizzle) ---
// grid 1024 blocks x 256 thr (4 independent waves). Swizzle: f=blockIdx.x ->
// bh=(f&7)+8*((f>>3)&1), i0=(f>>4)*64  => XCD x (= f%8) touches only bh {x,x+8}
// (1.5MB K/V, L2-resident). Wave w owns queries i0+16w..+15; lane 16g+m owns
// query i=16w+m. K frags double-buffered in registers (prefetch next tile).
__global__ __launch_bounds__(256, 4) void attn_mfma(
    const unsigned short* __restrict__ Qhi, const unsigned short* __restrict__ Qlo,
    const unsigned short* __restrict__ Khi, const unsigned short* __restrict__ Klo,
    const unsigned short* __restrict__ Vthi, float* __restrict__ out) {
  const int t = threadIdx.x;
  const int w = t >> 6, lane = t & 63, m = lane & 15, g = lane >> 4;
  const int f = blockIdx.x;
  const int i0 = (f >> 4) * 64;
  const int bh = (f & 7) + 8 * ((f >> 3) & 1);

  size_t qi = ((size_t)bh * NTOK + i0 + 16 * w + m) * HD + 8 * g;
  const bf16x8 qh = *(const bf16x8*)&Qhi[qi];
  const bf16x8 ql = *(const bf16x8*)&Qlo[qi];

  const unsigned short* Kb_h = Khi + (size_t)bh * NTOK * HD;
  const unsigned short* Kb_l = Klo + (size_t)bh * NTOK * HD;
  const unsigned short* Vb   = Vthi + (size_t)bh * HD * NTOK;

  f32x4 zero = {0.f, 0.f, 0.f, 0.f};
  f32x4 oacc[2] = {zero, zero};  // D[c=16ct+4g+r][i=m]
  float mrun = -1e30f, lrun = 0.f;
  const float scale = 0.17677669529663688f;  // 1/sqrt(32)

  const int srcA = (g & 1) * 32 + m;  // P B-frag gather base lane
  const bool ghi = (g >= 2);

  bf16x8 kf_h[2][4], kf_l[2][4];  // K double-buffer (static indices only)

#define LOADK(S, J0)                                                  \
  do {                                                                \
    _Pragma("unroll") for (int jt = 0; jt < 4; ++jt) {                \
      size_t ki = (size_t)((J0) + 16 * jt + m) * HD + 8 * g;          \
      kf_h[S][jt] = *(const bf16x8*)&Kb_h[ki];                        \
      kf_l[S][jt] = *(const bf16x8*)&Kb_l[ki];                        \
    }                                                                 \
  } while (0)

#define COMPUTE_TILE(S, J0)                                                    \
  do {                                                                         \
    bf16x8 vf[2][2]; /* V for THIS tile: latency hidden by QK^T+softmax */     \
    _Pragma("unroll") for (int k2 = 0; k2 < 2; ++k2)                           \
        _Pragma("unroll") for (int ct = 0; ct < 2; ++ct)                       \
            vf[k2][ct] = *(const bf16x8*)&Vb[(size_t)(16 * ct + m) * NTOK +    \
                                             (J0) + 32 * k2 + 8 * g];          \
    f32x4 s[4];                                                                \
    _Pragma("unroll") for (int jt = 0; jt < 4; ++jt) {                         \
      f32x4 a = zero;                                                          \
      a = __builtin_amdgcn_mfma_f32_16x16x32_bf16(kf_l[S][jt], qh, a, 0, 0, 0);\
      a = __builtin_amdgcn_mfma_f32_16x16x32_bf16(kf_h[S][jt], ql, a, 0, 0, 0);\
      a = __builtin_amdgcn_mfma_f32_16x16x32_bf16(kf_h[S][jt], qh, a, 0, 0, 0);\
      _Pragma("unroll") for (int r = 0; r < 4; ++r) s[jt][r] = a[r] * scale;   \
    }                                                                          \
    float mx = s[0][0];                                                        \
    _Pragma("unroll") for (int jt = 0; jt < 4; ++jt)                           \
        _Pragma("unroll") for (int r = 0; r < 4; ++r) mx = fmaxf(mx, s[jt][r]);\
    mx = fmaxf(mx, __shfl_xor(mx, 16, 64));                                    \
    mx = fmaxf(mx, __shfl_xor(mx, 32, 64));                                    \
    const float mnew = fmaxf(mrun, mx);                                        \
    const float sf = __expf(mrun - mnew);                                      \
    mrun = mnew;                                                               \
    float rsum = 0.f;                                                          \
    unsigned pw[4][2];                                                         \
    _Pragma("unroll") for (int jt = 0; jt < 4; ++jt) {                         \
      float p0 = __expf(s[jt][0] - mnew);                                      \
      float p1 = __expf(s[jt][1] - mnew);                                      \
      float p2 = __expf(s[jt][2] - mnew);                                      \
      float p3 = __expf(s[jt][3] - mnew);                                      \
      rsum += (p0 + p1) + (p2 + p3);                                           \
      pw[jt][0] = packbf(p0, p1);                                              \
      pw[jt][1] = packbf(p2, p3);                                              \
    }                                                                          \
    rsum += __shfl_xor(rsum, 16, 64);                                          \
    rsum += __shfl_xor(rsum, 32, 64);                                          \
    lrun = lrun * sf + rsum;                                                   \
    _Pragma("unroll") for (int ct = 0; ct < 2; ++ct)                           \
        _Pragma("unroll") for (int r = 0; r < 4; ++r) oacc[ct][r] *= sf;       \
    _Pragma("unroll") for (int k2 = 0; k2 < 2; ++k2) {                         \
      const int tA = 2 * k2, tB = 2 * k2 + 1;                                  \
      unsigned w0a = __shfl((int)pw[tA][0], srcA, 64);                         \
      unsigned w1a = __shfl((int)pw[tA][1], srcA, 64);                         \
      unsigned w2a = __shfl((int)pw[tA][0], srcA + 16, 64);                    \
      unsigned w3a = __shfl((int)pw[tA][1], srcA + 16, 64);                    \
      unsigned w0b = __shfl((int)pw[tB][0], srcA, 64);                         \
      unsigned w1b = __shfl((int)pw[tB][1], srcA, 64);                         \
      unsigned w2b = __shfl((int)pw[tB][0], srcA + 16, 64);                    \
      unsigned w3b = __shfl((int)pw[tB][1], srcA + 16, 64);                    \
      union { unsigned u[4]; bf16x8 v; } pf;                                   \
      pf.u[0] = ghi ? w0b : w0a;                                               \
      pf.u[1] = ghi ? w1b : w1a;                                               \
      pf.u[2] = ghi ? w2b : w2a;                                               \
      pf.u[3] = ghi ? w3b : w3a;                                               \
      oacc[0] = __builtin_amdgcn_mfma_f32_16x16x32_bf16(vf[k2][0], pf.v,       \
                                                        oacc[0], 0, 0, 0);     \
      oacc[1] = __builtin_amdgcn_mfma_f32_16x16x32_bf16(vf[k2][1], pf.v,       \
                                                        oacc[1], 0, 0, 0);     \
    }                                                                          \
  } while (0)

  LOADK(0, 0);
  for (int j0 = 0; j0 < NTOK; j0 += 128) {
    LOADK(1, j0 + 64);            // prefetch: in flight across COMPUTE(0)
    COMPUTE_TILE(0, j0);
    if (j0 + 128 < NTOK) LOADK(0, j0 + 128);  // in flight across COMPUTE(1)
    COMPUTE_TILE(1, j0 + 64);
  }
#undef LOADK
#undef COMPUTE_TILE

  // ---- epilogue: divide by l, direct stores (4x64B segments per instr) ----
  const float inv = 1.0f / lrun;
  const int b = bh >> 3, h = bh & 7;
#pragma unroll
  for (int ct = 0; ct < 2; ++ct)
#pragma unroll
    for (int r = 0; r < 4; ++r) {
      const int c = h * HD + 16 * ct + 4 * g + r;
      out[((size_t)b * CIN + c) * NTOK + i0 + 16 * w + m] = oacc[ct][r] * inv;
    }
}

extern "C" void kernel_launch(void* const* d_in, const int* in_sizes, int n_in,
                              void* d_out, int out_size, void* d_ws, size_t ws_size,
                              hipStream_t stream) {
  const float* x    = (const float*)d_in[0];
  const float* w    = (const float*)d_in[1];
  const float* bias = (const float*)d_in[2];
  float* outp = (float*)d_out;

  // Xt (split bf16) in d_out scratch: 8,388,608 B = out bytes.
  unsigned short* Xthi = (unsigned short*)d_out;
  unsigned short* Xtlo = Xthi + (size_t)B_ * NTOK * CIN;

  // ws: 5 arrays x 4 MB = 20 MB (<= 25.17 MB proven in rounds 1-2)
  unsigned short* ws = (unsigned short*)d_ws;
  const size_t SZ = (size_t)BH * NTOK * HD;
  unsigned short* Qhi_ = ws + 0 * SZ;
  unsigned short* Qlo_ = ws + 1 * SZ;
  unsigned short* Khi_ = ws + 2 * SZ;
  unsigned short* Klo_ = ws + 3 * SZ;
  unsigned short* Vthi_ = ws + 4 * SZ;

  xt_split<<<dim3(NTOK / 64, CIN / 64, B_), 256, 0, stream>>>(x, Xthi, Xtlo);
  qkv_proj<<<dim3(COUT / 64, NTOK / 64, B_), 256, 0, stream>>>(
      w, bias, Xthi, Xtlo, Qhi_, Qlo_, Khi_, Klo_, Vthi_);
  attn_mfma<<<dim3(1024), 256, 0, stream>>>(
      Qhi_, Qlo_, Khi_, Klo_, Vthi_, outp);
}